// Round 17
// baseline (648.275 us; speedup 1.0000x reference)
//
#include <hip/hip_runtime.h>
#include <hip/hip_bf16.h>
#include <math.h>

#define B_DIM 2048
#define L_DIM 2048
#define F_DIM 1024
#define H_DIM 4096
#define P_DIM 88

typedef unsigned short u16;
typedef short bf16x8 __attribute__((ext_vector_type(8)));
typedef float f32x4 __attribute__((ext_vector_type(4)));

// ---- bf16 split helpers (RNE) ----
__device__ __forceinline__ u16 f2bf(float x) {
    unsigned u = __float_as_uint(x);
    return (u16)((u + 0x7fffu + ((u >> 16) & 1u)) >> 16);
}
__device__ __forceinline__ float bf2f(u16 h) {
    return __uint_as_float(((unsigned)h) << 16);
}

// ---- async global->LDS, 16B per lane (dest = wave-uniform base + lane*16) ----
__device__ __forceinline__ void gload_lds16(const void* g, void* l) {
    unsigned loff = (unsigned)(uintptr_t)l;
    __builtin_amdgcn_global_load_lds(
        reinterpret_cast<const __attribute__((address_space(1))) void*>(
            reinterpret_cast<uintptr_t>(g)),
        reinterpret_cast<__attribute__((address_space(3))) void*>(loff),
        16, 0, 0);
}

// ---- shared conv body: w[2][Kc][Nh] fp32 -> BT [2*Nh][4*Kc] split-bf16 ----
__device__ __forceinline__ void conv_body(
    const float* __restrict__ w, u16* __restrict__ BT, int Kc, int Nh,
    int k0, int n0, int tx, int ty, float (*t0s)[33], float (*t1s)[33])
{
    const float* w0 = w;
    const float* w1b = w + (size_t)Kc * Nh;

#pragma unroll
    for (int i = 0; i < 4; i++) {
        int k = k0 + ty + 8 * i;
        t0s[ty + 8 * i][tx] = w0[(size_t)k * Nh + n0 + tx];
        t1s[ty + 8 * i][tx] = w1b[(size_t)k * Nh + n0 + tx];
    }
    __syncthreads();

    size_t K4 = 4 * (size_t)Kc;
    int k = k0 + tx;
#pragma unroll
    for (int i = 0; i < 4; i++) {
        int nl = ty + 8 * i;
        int n = n0 + nl;
        float br = t0s[tx][nl];
        float bi = t1s[tx][nl];
        u16 brh = f2bf(br); u16 brl = f2bf(br - bf2f(brh));
        float nbi = -bi;
        u16 nih = f2bf(nbi); u16 nil = f2bf(nbi - bf2f(nih));
        u16 pih = f2bf(bi);  u16 pil = f2bf(bi - bf2f(pih));
        u16* rowr = BT + (size_t)n * K4;
        rowr[0 * Kc + k] = brh; rowr[1 * Kc + k] = brl;
        rowr[2 * Kc + k] = nih; rowr[3 * Kc + k] = nil;
        u16* rowi = BT + (size_t)(Nh + n) * K4;
        rowi[0 * Kc + k] = pih; rowi[1 * Kc + k] = pil;
        rowi[2 * Kc + k] = brh; rowi[3 * Kc + k] = brl;
    }
}

// ---------------------------------------------------------------------------
// Fused prep: blocks [0,1024) = start_fc + real-pair FFT -> A1;
// blocks [1024,5120) = conv w1 -> BT1; blocks [5120,9216) = conv w2 -> BT2.
// ---------------------------------------------------------------------------
__global__ __launch_bounds__(256) void prep_kernel(
    const float* __restrict__ x, const float* __restrict__ w_start,
    const float* __restrict__ b_start, u16* __restrict__ A1,
    const float* __restrict__ w1, u16* __restrict__ BT1,
    const float* __restrict__ w2, u16* __restrict__ BT2)
{
    __shared__ float re[2048];
    __shared__ float im[2048];
    __shared__ float twr[1024];
    __shared__ float twi[1024];
    __shared__ float t0s[32][33];
    __shared__ float t1s[32][33];

    const int tid = threadIdx.x;

    if (blockIdx.x < 1024) {
        int b = blockIdx.x;                       // pair index 0..1023
        const size_t row0 = (size_t)(2 * b) * 2048;

        const float4* wp = (const float4*)w_start;
        float4 w0 = wp[0], w1v = wp[1], w2v = wp[2], w3 = wp[3];
        float bs = b_start[0];

        for (int i = tid; i < 1024; i += 256) {
            float ang = -6.283185307179586f * ((float)i / 2048.0f);
            sincosf(ang, &twi[i], &twr[i]);
        }

        for (int l = tid; l < 2048; l += 256) {
            const float4* xp0 = (const float4*)(x + (row0 + l) * 16);
            const float4* xp1 = (const float4*)(x + (row0 + 2048 + l) * 16);
            float4 a0 = xp0[0], a1 = xp0[1], a2 = xp0[2], a3 = xp0[3];
            float4 c0 = xp1[0], c1 = xp1[1], c2 = xp1[2], c3 = xp1[3];
            float va = bs, vb = bs;
            va += a0.x * w0.x + a0.y * w0.y + a0.z * w0.z + a0.w * w0.w;
            va += a1.x * w1v.x + a1.y * w1v.y + a1.z * w1v.z + a1.w * w1v.w;
            va += a2.x * w2v.x + a2.y * w2v.y + a2.z * w2v.z + a2.w * w2v.w;
            va += a3.x * w3.x + a3.y * w3.y + a3.z * w3.z + a3.w * w3.w;
            vb += c0.x * w0.x + c0.y * w0.y + c0.z * w0.z + c0.w * w0.w;
            vb += c1.x * w1v.x + c1.y * w1v.y + c1.z * w1v.z + c1.w * w1v.w;
            vb += c2.x * w2v.x + c2.y * w2v.y + c2.z * w2v.z + c2.w * w2v.w;
            vb += c3.x * w3.x + c3.y * w3.y + c3.z * w3.z + c3.w * w3.w;
            unsigned j = __brev((unsigned)l) >> 21;   // bit-reversed position
            re[j] = va;
            im[j] = vb;
        }
        __syncthreads();

        for (int s = 1; s <= 11; s++) {
            int half = 1 << (s - 1);
            for (int t = tid; t < 1024; t += 256) {
                int j = t & (half - 1);
                int base = (t >> (s - 1)) << s;
                int idx = j << (11 - s);
                float wr = twr[idx], wi = twi[idx];
                int i0 = base + j, i1 = i0 + half;
                float br = re[i1], bi = im[i1];
                float tr = br * wr - bi * wi;
                float ti = br * wi + bi * wr;
                float ar = re[i0], ai = im[i0];
                re[i0] = ar + tr; im[i0] = ai + ti;
                re[i1] = ar - tr; im[i1] = ai - ti;
            }
            __syncthreads();
        }

        const float sc = 0.5f * 0.022097086912079612f;  // 0.5 / sqrt(2048)
        u16* r0 = A1 + (size_t)(2 * b) * 4096;
        u16* r1 = r0 + 4096;
        for (int t = tid; t < 1024; t += 256) {
            int k = t + 1;
            int nk = 2048 - k;
            float Zr = re[k], Zi = im[k], Yr = re[nk], Yi = im[nk];
            float Ar = (Zr + Yr) * sc;
            float Ai = (Zi - Yi) * sc;
            float Br = (Zi + Yi) * sc;
            float Bi = (Yr - Zr) * sc;
            u16 h, lo;
            h = f2bf(Ar); lo = f2bf(Ar - bf2f(h)); r0[t] = h; r0[1024 + t] = lo;
            h = f2bf(Ai); lo = f2bf(Ai - bf2f(h)); r0[2048 + t] = h; r0[3072 + t] = lo;
            h = f2bf(Br); lo = f2bf(Br - bf2f(h)); r1[t] = h; r1[1024 + t] = lo;
            h = f2bf(Bi); lo = f2bf(Bi - bf2f(h)); r1[2048 + t] = h; r1[3072 + t] = lo;
        }
    } else if (blockIdx.x < 5120) {
        int bid = blockIdx.x - 1024;               // conv1: 32 k-blk x 128 n-blk
        int k0 = (bid & 31) * 32;
        int n0 = (bid >> 5) * 32;
        conv_body(w1, BT1, F_DIM, H_DIM, k0, n0, tid & 31, tid >> 5, t0s, t1s);
    } else {
        int bid = blockIdx.x - 5120;               // conv2: 128 k-blk x 32 n-blk
        int k0 = (bid & 127) * 32;
        int n0 = (bid >> 7) * 32;
        conv_body(w2, BT2, H_DIM, F_DIM, k0, n0, tid & 31, tid >> 5, t0s, t1s);
    }
}

// ---------------------------------------------------------------------------
// Standalone conv (w2) for the non-fused workspace path.
// ---------------------------------------------------------------------------
__global__ __launch_bounds__(256) void conv_bt_kernel(
    const float* __restrict__ w, u16* __restrict__ BT, int Kc, int Nh)
{
    __shared__ float t0[32][33];
    __shared__ float t1[32][33];
    conv_body(w, BT, Kc, Nh, blockIdx.x * 32, blockIdx.y * 32,
              threadIdx.x, threadIdx.y, t0, t1);
}

// ---------------------------------------------------------------------------
// 16-wave split-bf16 GEMM — 2-tile blocks, 4x-UNROLLED (ring period) so all
// LDS slot offsets are compile-time constants; staging addr = per-thread base
// + wave-uniform col (SALU). Strength-reduces the ~615 cyc/SIMD/tile VALU
// address arithmetic identified as the plateau's third pipe.
// NT = K32-tiles per z-slice (template const, divisible by 4).
// SWZ=1: XCD grid (layer 1). SWZ=2: XCD-pinned A-panels + split-K (layer 2).
// ---------------------------------------------------------------------------
extern __shared__ char smem8p[];

#define MFMA8(I0, I1, A0, A1)                                                       \
    acc[I0][0] = __builtin_amdgcn_mfma_f32_16x16x32_bf16(A0, b0, acc[I0][0], 0, 0, 0); \
    acc[I0][1] = __builtin_amdgcn_mfma_f32_16x16x32_bf16(A0, b1, acc[I0][1], 0, 0, 0); \
    acc[I0][2] = __builtin_amdgcn_mfma_f32_16x16x32_bf16(A0, b2, acc[I0][2], 0, 0, 0); \
    acc[I0][3] = __builtin_amdgcn_mfma_f32_16x16x32_bf16(A0, b3, acc[I0][3], 0, 0, 0); \
    acc[I1][0] = __builtin_amdgcn_mfma_f32_16x16x32_bf16(A1, b0, acc[I1][0], 0, 0, 0); \
    acc[I1][1] = __builtin_amdgcn_mfma_f32_16x16x32_bf16(A1, b1, acc[I1][1], 0, 0, 0); \
    acc[I1][2] = __builtin_amdgcn_mfma_f32_16x16x32_bf16(A1, b2, acc[I1][2], 0, 0, 0); \
    acc[I1][3] = __builtin_amdgcn_mfma_f32_16x16x32_bf16(A1, b3, acc[I1][3], 0, 0, 0);

#define RD(P, OFF) (*(const bf16x8*)((P) + (OFF)))

template <int EPI, int SWZ, int NT>
__global__ __launch_bounds__(1024, 4) void gemm8p(
    const u16* __restrict__ A, const u16* __restrict__ B,
    const float* __restrict__ biasL, const float* __restrict__ biasR,
    u16* __restrict__ OutU, float* __restrict__ P01, float* __restrict__ P23,
    int Kc, int KcLog, int NH)
{
    char* ldsA = smem8p;
    char* ldsB = smem8p + 65536;

    const int tid = threadIdx.x;
    const int w = tid >> 6, lane = tid & 63;
    const int wr = w >> 2, wc = w & 3;
    const int fr = lane & 15, kb = lane >> 4;

    int bx, by, z;
    if (SWZ == 1) {
        int b = blockIdx.x;
        int xcd = b & 7, idx = b >> 3;
        bx = 4 * xcd + (idx & 3);
        by = idx >> 2;
        z = 0;
    } else if (SWZ == 2) {
        int b = blockIdx.x;
        by = b & 7;
        int s = b >> 3;
        bx = s & 7;
        z = s >> 3;
    } else {
        bx = blockIdx.x; by = blockIdx.y; z = blockIdx.z;
    }
    const int n0 = bx * 256, m0 = by * 256;
    const size_t K4 = 4 * (size_t)Kc;

    // staging: per-thread base pointers (precomputed once), uniform col adds
    const int srow = tid >> 2;
    const int lk8 = (((tid & 3) ^ ((tid >> 3) & 3))) * 8;
    const u16* baseA = A + (size_t)(m0 + srow) * K4 + lk8;
    const u16* baseB = B + (size_t)(n0 + srow) * K4 + lk8;
    const int wb = w * 1024;
    char* dA0 = ldsA + 0 * 16384 + wb;  char* dA1 = ldsA + 1 * 16384 + wb;
    char* dA2 = ldsA + 2 * 16384 + wb;  char* dA3 = ldsA + 3 * 16384 + wb;
    char* dB0 = ldsB + 0 * 16384 + wb;  char* dB1 = ldsB + 1 * 16384 + wb;
    char* dB2 = ldsB + 2 * 16384 + wb;  char* dB3 = ldsB + 3 * 16384 + wb;

    // frag-read base pointers per slot (static offsets within)
    const int laneOff = fr * 64 + ((kb ^ ((fr >> 1) & 3)) << 4);
    const char* aB0 = ldsA + 0 * 16384 + wr * 4096 + laneOff;
    const char* aB1 = ldsA + 1 * 16384 + wr * 4096 + laneOff;
    const char* aB2 = ldsA + 2 * 16384 + wr * 4096 + laneOff;
    const char* aB3 = ldsA + 3 * 16384 + wr * 4096 + laneOff;
    const char* bB0 = ldsB + 0 * 16384 + wc * 4096 + laneOff;
    const char* bB1 = ldsB + 1 * 16384 + wc * 4096 + laneOff;
    const char* bB2 = ldsB + 2 * 16384 + wc * 4096 + laneOff;
    const char* bB3 = ldsB + 3 * 16384 + wc * 4096 + laneOff;

    f32x4 acc[4][4];
#pragma unroll
    for (int i = 0; i < 4; i++)
#pragma unroll
        for (int j = 0; j < 4; j++)
            acc[i][j] = (f32x4){0.f, 0.f, 0.f, 0.f};

    const int t0 = z * NT;

    auto colA = [&](int t) {
        int k0 = t << 5;
        int seg = k0 >> KcLog, kk = k0 & (Kc - 1);
        int r3 = seg >= 3 ? seg - 3 : seg;
        int bs = seg >= 3 ? 2 : 0;
        return (bs + (r3 == 1 ? 1 : 0)) * Kc + kk;
    };
    auto colB = [&](int t) {
        int k0 = t << 5;
        int seg = k0 >> KcLog, kk = k0 & (Kc - 1);
        int r3 = seg >= 3 ? seg - 3 : seg;
        int bs = seg >= 3 ? 2 : 0;
        return (bs + (r3 == 2 ? 1 : 0)) * Kc + kk;
    };

    // prologue: stage tiles t0,t0+1 into slots 0,1; publish; read tile-0 frags
    gload_lds16(baseA + colA(t0 + 0), dA0);
    gload_lds16(baseB + colB(t0 + 0), dB0);
    gload_lds16(baseA + colA(t0 + 1), dA1);
    gload_lds16(baseB + colB(t0 + 1), dB1);
    asm volatile("s_waitcnt vmcnt(0)" ::: "memory");
    asm volatile("s_barrier" ::: "memory");

    bf16x8 a0 = RD(aB0, 0),   a1 = RD(aB0, 1024);
    bf16x8 b0 = RD(bB0, 0),   b1 = RD(bB0, 1024);
    bf16x8 b2 = RD(bB0, 2048), b3 = RD(bB0, 3072);
    bf16x8 c0, c1;

    for (int i = 0; i < NT / 4; ++i) {
        const int tb = t0 + 4 * i;
        const bool more = (i + 1 < NT / 4);

        // ======== Block 0: tiles tb,tb+1 (slots 0,1); stage slots 2,3 ========
        gload_lds16(baseA + colA(tb + 2), dA2);
        gload_lds16(baseB + colB(tb + 2), dB2);
        gload_lds16(baseA + colA(tb + 3), dA3);
        gload_lds16(baseB + colB(tb + 3), dB3);

        // tile tb (slot 0)
        c0 = RD(aB0, 2048); c1 = RD(aB0, 3072);
        MFMA8(0, 1, a0, a1)
        a0 = RD(aB1, 0); a1 = RD(aB1, 1024);
        MFMA8(2, 3, c0, c1)

        // tile tb+1 (slot 1)
        b0 = RD(bB1, 0); b1 = RD(bB1, 1024); b2 = RD(bB1, 2048); b3 = RD(bB1, 3072);
        c0 = RD(aB1, 2048); c1 = RD(aB1, 3072);
        MFMA8(0, 1, a0, a1)
        MFMA8(2, 3, c0, c1)

        asm volatile("s_waitcnt vmcnt(0)" ::: "memory");
        asm volatile("s_barrier" ::: "memory");
        a0 = RD(aB2, 0); a1 = RD(aB2, 1024);
        b0 = RD(bB2, 0); b1 = RD(bB2, 1024); b2 = RD(bB2, 2048); b3 = RD(bB2, 3072);

        // ======== Block 1: tiles tb+2,tb+3 (slots 2,3); stage slots 0,1 ======
        if (more) {
            gload_lds16(baseA + colA(tb + 4), dA0);
            gload_lds16(baseB + colB(tb + 4), dB0);
            gload_lds16(baseA + colA(tb + 5), dA1);
            gload_lds16(baseB + colB(tb + 5), dB1);
        }

        // tile tb+2 (slot 2)
        c0 = RD(aB2, 2048); c1 = RD(aB2, 3072);
        MFMA8(0, 1, a0, a1)
        a0 = RD(aB3, 0); a1 = RD(aB3, 1024);
        MFMA8(2, 3, c0, c1)

        // tile tb+3 (slot 3)
        b0 = RD(bB3, 0); b1 = RD(bB3, 1024); b2 = RD(bB3, 2048); b3 = RD(bB3, 3072);
        c0 = RD(aB3, 2048); c1 = RD(aB3, 3072);
        MFMA8(0, 1, a0, a1)
        MFMA8(2, 3, c0, c1)

        if (more) {
            asm volatile("s_waitcnt vmcnt(0)" ::: "memory");
            asm volatile("s_barrier" ::: "memory");
            a0 = RD(aB0, 0); a1 = RD(aB0, 1024);
            b0 = RD(bB0, 0); b1 = RD(bB0, 1024); b2 = RD(bB0, 2048); b3 = RD(bB0, 3072);
        }
    }

    // ---- epilogue (wave-tile 64x64 at (wr*64, wc*64)) ----
    const int fq = kb;
#pragma unroll
    for (int nj = 0; nj < 4; nj++) {
        int n = n0 + wc * 64 + nj * 16 + fr;
        if (EPI == 0) {
            bool left = (n < NH);
            int nn = left ? n : (n - NH);
            float bias = left ? biasL[n] : biasR[nn];
#pragma unroll
            for (int mi = 0; mi < 4; mi++) {
                int mb = m0 + wr * 64 + mi * 16 + fq * 4;
#pragma unroll
                for (int r = 0; r < 4; r++) {
                    float val = fmaxf(acc[mi][nj][r] + bias, 0.f);
                    u16 h = f2bf(val);
                    u16 lo = f2bf(val - bf2f(h));
                    size_t rb = (size_t)(mb + r) * (4 * (size_t)NH);
                    if (left) { OutU[rb + nn] = h; OutU[rb + NH + nn] = lo; }
                    else { OutU[rb + 2 * (size_t)NH + nn] = h; OutU[rb + 3 * (size_t)NH + nn] = lo; }
                }
            }
        } else {
            const size_t PSZ = (size_t)2048 * 2048;
            float* Out = (z < 2) ? (P01 + (size_t)z * PSZ) : (P23 + (size_t)(z - 2) * PSZ);
#pragma unroll
            for (int mi = 0; mi < 4; mi++) {
                int mb = m0 + wr * 64 + mi * 16 + fq * 4;
#pragma unroll
                for (int r = 0; r < 4; r++)
                    Out[(size_t)(mb + r) * 2048 + n] = acc[mi][nj][r];
            }
        }
    }
}

// ---------------------------------------------------------------------------
// Router, 8 rows/block
// ---------------------------------------------------------------------------
__global__ __launch_bounds__(256) void router_kernel(
    const float* __restrict__ P01, const float* __restrict__ P23, int ZK,
    const float* __restrict__ b2,
    const float* __restrict__ w_gate, const float* __restrict__ w_noise,
    const float* __restrict__ noise_z, float* __restrict__ gates)
{
    __shared__ float s_amp[8][1024];
    __shared__ float s_dot[8][176];
    __shared__ float s_lg[8][88];
    __shared__ int   s_idx[8][3];
    __shared__ float s_val[8][3];

    const int tid = threadIdx.x;
    const int r0 = blockIdx.x * 8;
    const size_t PSZ = (size_t)2048 * 2048;

    for (int idx = tid; idx < 8 * 1024; idx += 256) {
        int row = idx >> 10, i = idx & 1023;
        size_t roff = (size_t)(r0 + row) * 2048;
        float orr = b2[i];
        float oii = b2[1024 + i];
        for (int zz = 0; zz < ZK; zz++) {
            const float* Pz = ((zz < 2) ? (P01 + (size_t)zz * PSZ)
                                        : (P23 + (size_t)(zz - 2) * PSZ)) + roff;
            orr += Pz[i];
            oii += Pz[1024 + i];
        }
        s_amp[row][i] = sqrtf(orr * orr + oii * oii);
    }
    __syncthreads();

    for (int idx = tid; idx < 8 * 176; idx += 256) {
        int row = idx / 176, c = idx % 176;
        const float* wcol = (c < 88) ? (w_gate + c) : (w_noise + (c - 88));
        float s = 0.f;
        const float4* av = (const float4*)s_amp[row];
        for (int k4 = 0; k4 < 256; k4++) {
            float4 a = av[k4];
            int k = k4 * 4;
            s = fmaf(a.x, wcol[(size_t)(k + 0) * 88], s);
            s = fmaf(a.y, wcol[(size_t)(k + 1) * 88], s);
            s = fmaf(a.z, wcol[(size_t)(k + 2) * 88], s);
            s = fmaf(a.w, wcol[(size_t)(k + 3) * 88], s);
        }
        s_dot[row][c] = s;
    }
    __syncthreads();

    for (int idx = tid; idx < 8 * 88; idx += 256) {
        int row = idx / 88, c = idx % 88;
        float cn = s_dot[row][88 + c];
        float ns = (cn > 20.f) ? cn : log1pf(expf(cn));
        ns += 0.01f;
        s_lg[row][c] = s_dot[row][c] + noise_z[(size_t)(r0 + row) * 88 + c] * ns;
    }
    __syncthreads();

    if (tid < 8) {
        int i0 = -1, i1 = -1, i2 = -1;
        float v0 = -1e30f, v1 = -1e30f, v2 = -1e30f;
        for (int i = 0; i < P_DIM; i++) {
            float t = s_lg[tid][i];
            if (t > v0) { v0 = t; i0 = i; }
        }
        for (int i = 0; i < P_DIM; i++) {
            if (i == i0) continue;
            float t = s_lg[tid][i];
            if (t > v1) { v1 = t; i1 = i; }
        }
        for (int i = 0; i < P_DIM; i++) {
            if (i == i0 || i == i1) continue;
            float t = s_lg[tid][i];
            if (t > v2) { v2 = t; i2 = i; }
        }
        s_idx[tid][0] = i0; s_idx[tid][1] = i1; s_idx[tid][2] = i2;
        s_val[tid][0] = v0; s_val[tid][1] = v1; s_val[tid][2] = v2;
    }
    __syncthreads();

    for (int idx = tid; idx < 8 * 88; idx += 256) {
        int row = idx / 88, c = idx % 88;
        float m = s_val[row][0];
        float e0 = expf(s_val[row][0] - m);
        float e1 = expf(s_val[row][1] - m);
        float e2 = expf(s_val[row][2] - m);
        float inv = 1.f / (e0 + e1 + e2);
        float g = 0.f;
        if (c == s_idx[row][0]) g = e0 * inv;
        else if (c == s_idx[row][1]) g = e1 * inv;
        else if (c == s_idx[row][2]) g = e2 * inv;
        gates[(size_t)(r0 + row) * 88 + c] = g;
    }
}

// ---------------------------------------------------------------------------
extern "C" void kernel_launch(void* const* d_in, const int* in_sizes, int n_in,
                              void* d_out, int out_size, void* d_ws, size_t ws_size,
                              hipStream_t stream)
{
    const float* x       = (const float*)d_in[0];
    const float* w_start = (const float*)d_in[1];
    const float* b_start = (const float*)d_in[2];
    const float* w1      = (const float*)d_in[3];
    const float* b1      = (const float*)d_in[4];
    const float* w2      = (const float*)d_in[5];
    const float* b2      = (const float*)d_in[6];
    const float* w_gate  = (const float*)d_in[7];
    const float* w_noise = (const float*)d_in[8];
    const float* noise_z = (const float*)d_in[9];
    float* gates = (float*)d_out;

    const size_t MB = 1024 * 1024;
    char* base = (char*)d_ws;

    hipFuncSetAttribute(reinterpret_cast<const void*>(&gemm8p<0, 1, 192>),
                        hipFuncAttributeMaxDynamicSharedMemorySize, 131072);
    hipFuncSetAttribute(reinterpret_cast<const void*>(&gemm8p<1, 2, 192>),
                        hipFuncAttributeMaxDynamicSharedMemorySize, 131072);
    hipFuncSetAttribute(reinterpret_cast<const void*>(&gemm8p<1, 2, 384>),
                        hipFuncAttributeMaxDynamicSharedMemorySize, 131072);

    if (ws_size >= (size_t)208 * MB) {
        // fused layout: BT1[0,64) A1[64,80) BT2[80,144) A2[144,208);
        // P01 [0,32), P23 [32,64) overlay BT1 after gemm1.
        u16*  BT1 = (u16*)base;
        u16*  A1  = (u16*)(base + 64 * MB);
        u16*  BT2 = (u16*)(base + 80 * MB);
        u16*  A2  = (u16*)(base + 144 * MB);
        float* P01 = (float*)base;
        float* P23 = (float*)(base + 32 * MB);

        prep_kernel<<<1024 + 4096 + 4096, 256, 0, stream>>>(
            x, w_start, b_start, A1, w1, BT1, w2, BT2);

        gemm8p<0, 1, 192><<<256, 1024, 131072, stream>>>(
            A1, BT1, b1, b1 + H_DIM, A2, nullptr, nullptr, F_DIM, 10, H_DIM);

        gemm8p<1, 2, 192><<<64 * 4, 1024, 131072, stream>>>(
            A2, BT2, nullptr, nullptr, nullptr, P01, P23, H_DIM, 12, F_DIM);

        router_kernel<<<B_DIM / 8, 256, 0, stream>>>(
            P01, P23, 4, b2, w_gate, w_noise, noise_z, gates);
    } else {
        // fallback layout: A1[16,32) BT[32,96) A2[96,160); P01[0,32) P23[160,192)
        u16*  A1  = (u16*)(base + 16 * MB);
        u16*  BT  = (u16*)(base + 32 * MB);
        u16*  A2  = (u16*)(base + 96 * MB);
        float* P01 = (float*)base;
        float* P23 = (float*)(base + 160 * MB);
        int ZK = (ws_size >= (size_t)192 * MB) ? 4 : 2;

        prep_kernel<<<1024 + 4096, 256, 0, stream>>>(
            x, w_start, b_start, A1, w1, BT, w2, BT /*unused range*/);

        gemm8p<0, 1, 192><<<256, 1024, 131072, stream>>>(
            A1, BT, b1, b1 + H_DIM, A2, nullptr, nullptr, F_DIM, 10, H_DIM);

        conv_bt_kernel<<<dim3(H_DIM / 32, F_DIM / 32), dim3(32, 8), 0, stream>>>(
            w2, BT, H_DIM, F_DIM);
        if (ZK == 4) {
            gemm8p<1, 2, 192><<<64 * 4, 1024, 131072, stream>>>(
                A2, BT, nullptr, nullptr, nullptr, P01, P23, H_DIM, 12, F_DIM);
        } else {
            gemm8p<1, 2, 384><<<64 * 2, 1024, 131072, stream>>>(
                A2, BT, nullptr, nullptr, nullptr, P01, P23, H_DIM, 12, F_DIM);
        }

        router_kernel<<<B_DIM / 8, 256, 0, stream>>>(
            P01, P23, ZK, b2, w_gate, w_noise, noise_z, gates);
    }
}

// Round 18
// 567.213 us; speedup vs baseline: 1.1429x; 1.1429x over previous
//
#include <hip/hip_runtime.h>
#include <hip/hip_bf16.h>
#include <math.h>

#define B_DIM 2048
#define L_DIM 2048
#define F_DIM 1024
#define H_DIM 4096
#define P_DIM 88

typedef unsigned short u16;
typedef short bf16x8 __attribute__((ext_vector_type(8)));
typedef float f32x4 __attribute__((ext_vector_type(4)));

// ---- bf16 split helpers (RNE) ----
__device__ __forceinline__ u16 f2bf(float x) {
    unsigned u = __float_as_uint(x);
    return (u16)((u + 0x7fffu + ((u >> 16) & 1u)) >> 16);
}
__device__ __forceinline__ float bf2f(u16 h) {
    return __uint_as_float(((unsigned)h) << 16);
}

// ---- async global->LDS, 16B per lane (dest = wave-uniform base + lane*16) ----
__device__ __forceinline__ void gload_lds16(const void* g, void* l) {
    unsigned loff = (unsigned)(uintptr_t)l;
    __builtin_amdgcn_global_load_lds(
        reinterpret_cast<const __attribute__((address_space(1))) void*>(
            reinterpret_cast<uintptr_t>(g)),
        reinterpret_cast<__attribute__((address_space(3))) void*>(loff),
        16, 0, 0);
}

// ---- shared conv body: w[2][Kc][Nh] fp32 -> BT [2*Nh][4*Kc] split-bf16 ----
__device__ __forceinline__ void conv_body(
    const float* __restrict__ w, u16* __restrict__ BT, int Kc, int Nh,
    int k0, int n0, int tx, int ty, float (*t0s)[33], float (*t1s)[33])
{
    const float* w0 = w;
    const float* w1b = w + (size_t)Kc * Nh;

#pragma unroll
    for (int i = 0; i < 4; i++) {
        int k = k0 + ty + 8 * i;
        t0s[ty + 8 * i][tx] = w0[(size_t)k * Nh + n0 + tx];
        t1s[ty + 8 * i][tx] = w1b[(size_t)k * Nh + n0 + tx];
    }
    __syncthreads();

    size_t K4 = 4 * (size_t)Kc;
    int k = k0 + tx;
#pragma unroll
    for (int i = 0; i < 4; i++) {
        int nl = ty + 8 * i;
        int n = n0 + nl;
        float br = t0s[tx][nl];
        float bi = t1s[tx][nl];
        u16 brh = f2bf(br); u16 brl = f2bf(br - bf2f(brh));
        float nbi = -bi;
        u16 nih = f2bf(nbi); u16 nil = f2bf(nbi - bf2f(nih));
        u16 pih = f2bf(bi);  u16 pil = f2bf(bi - bf2f(pih));
        u16* rowr = BT + (size_t)n * K4;
        rowr[0 * Kc + k] = brh; rowr[1 * Kc + k] = brl;
        rowr[2 * Kc + k] = nih; rowr[3 * Kc + k] = nil;
        u16* rowi = BT + (size_t)(Nh + n) * K4;
        rowi[0 * Kc + k] = pih; rowi[1 * Kc + k] = pil;
        rowi[2 * Kc + k] = brh; rowi[3 * Kc + k] = brl;
    }
}

// ---------------------------------------------------------------------------
// Fused prep: blocks [0,1024) = start_fc + real-pair FFT -> A1;
// blocks [1024,5120) = conv w1 -> BT1; blocks [5120,9216) = conv w2 -> BT2.
// ---------------------------------------------------------------------------
__global__ __launch_bounds__(256) void prep_kernel(
    const float* __restrict__ x, const float* __restrict__ w_start,
    const float* __restrict__ b_start, u16* __restrict__ A1,
    const float* __restrict__ w1, u16* __restrict__ BT1,
    const float* __restrict__ w2, u16* __restrict__ BT2)
{
    __shared__ float re[2048];
    __shared__ float im[2048];
    __shared__ float twr[1024];
    __shared__ float twi[1024];
    __shared__ float t0s[32][33];
    __shared__ float t1s[32][33];

    const int tid = threadIdx.x;

    if (blockIdx.x < 1024) {
        int b = blockIdx.x;                       // pair index 0..1023
        const size_t row0 = (size_t)(2 * b) * 2048;

        const float4* wp = (const float4*)w_start;
        float4 w0 = wp[0], w1v = wp[1], w2v = wp[2], w3 = wp[3];
        float bs = b_start[0];

        for (int i = tid; i < 1024; i += 256) {
            float ang = -6.283185307179586f * ((float)i / 2048.0f);
            sincosf(ang, &twi[i], &twr[i]);
        }

        for (int l = tid; l < 2048; l += 256) {
            const float4* xp0 = (const float4*)(x + (row0 + l) * 16);
            const float4* xp1 = (const float4*)(x + (row0 + 2048 + l) * 16);
            float4 a0 = xp0[0], a1 = xp0[1], a2 = xp0[2], a3 = xp0[3];
            float4 c0 = xp1[0], c1 = xp1[1], c2 = xp1[2], c3 = xp1[3];
            float va = bs, vb = bs;
            va += a0.x * w0.x + a0.y * w0.y + a0.z * w0.z + a0.w * w0.w;
            va += a1.x * w1v.x + a1.y * w1v.y + a1.z * w1v.z + a1.w * w1v.w;
            va += a2.x * w2v.x + a2.y * w2v.y + a2.z * w2v.z + a2.w * w2v.w;
            va += a3.x * w3.x + a3.y * w3.y + a3.z * w3.z + a3.w * w3.w;
            vb += c0.x * w0.x + c0.y * w0.y + c0.z * w0.z + c0.w * w0.w;
            vb += c1.x * w1v.x + c1.y * w1v.y + c1.z * w1v.z + c1.w * w1v.w;
            vb += c2.x * w2v.x + c2.y * w2v.y + c2.z * w2v.z + c2.w * w2v.w;
            vb += c3.x * w3.x + c3.y * w3.y + c3.z * w3.z + c3.w * w3.w;
            unsigned j = __brev((unsigned)l) >> 21;   // bit-reversed position
            re[j] = va;
            im[j] = vb;
        }
        __syncthreads();

        for (int s = 1; s <= 11; s++) {
            int half = 1 << (s - 1);
            for (int t = tid; t < 1024; t += 256) {
                int j = t & (half - 1);
                int base = (t >> (s - 1)) << s;
                int idx = j << (11 - s);
                float wr = twr[idx], wi = twi[idx];
                int i0 = base + j, i1 = i0 + half;
                float br = re[i1], bi = im[i1];
                float tr = br * wr - bi * wi;
                float ti = br * wi + bi * wr;
                float ar = re[i0], ai = im[i0];
                re[i0] = ar + tr; im[i0] = ai + ti;
                re[i1] = ar - tr; im[i1] = ai - ti;
            }
            __syncthreads();
        }

        const float sc = 0.5f * 0.022097086912079612f;  // 0.5 / sqrt(2048)
        u16* r0 = A1 + (size_t)(2 * b) * 4096;
        u16* r1 = r0 + 4096;
        for (int t = tid; t < 1024; t += 256) {
            int k = t + 1;
            int nk = 2048 - k;
            float Zr = re[k], Zi = im[k], Yr = re[nk], Yi = im[nk];
            float Ar = (Zr + Yr) * sc;
            float Ai = (Zi - Yi) * sc;
            float Br = (Zi + Yi) * sc;
            float Bi = (Yr - Zr) * sc;
            u16 h, lo;
            h = f2bf(Ar); lo = f2bf(Ar - bf2f(h)); r0[t] = h; r0[1024 + t] = lo;
            h = f2bf(Ai); lo = f2bf(Ai - bf2f(h)); r0[2048 + t] = h; r0[3072 + t] = lo;
            h = f2bf(Br); lo = f2bf(Br - bf2f(h)); r1[t] = h; r1[1024 + t] = lo;
            h = f2bf(Bi); lo = f2bf(Bi - bf2f(h)); r1[2048 + t] = h; r1[3072 + t] = lo;
        }
    } else if (blockIdx.x < 5120) {
        int bid = blockIdx.x - 1024;               // conv1: 32 k-blk x 128 n-blk
        int k0 = (bid & 31) * 32;
        int n0 = (bid >> 5) * 32;
        conv_body(w1, BT1, F_DIM, H_DIM, k0, n0, tid & 31, tid >> 5, t0s, t1s);
    } else {
        int bid = blockIdx.x - 5120;               // conv2: 128 k-blk x 32 n-blk
        int k0 = (bid & 127) * 32;
        int n0 = (bid >> 7) * 32;
        conv_body(w2, BT2, H_DIM, F_DIM, k0, n0, tid & 31, tid >> 5, t0s, t1s);
    }
}

// ---------------------------------------------------------------------------
// Standalone conv (w2) for the non-fused workspace path.
// ---------------------------------------------------------------------------
__global__ __launch_bounds__(256) void conv_bt_kernel(
    const float* __restrict__ w, u16* __restrict__ BT, int Kc, int Nh)
{
    __shared__ float t0[32][33];
    __shared__ float t1[32][33];
    conv_body(w, BT, Kc, Nh, blockIdx.x * 32, blockIdx.y * 32,
              threadIdx.x, threadIdx.y, t0, t1);
}

// ---------------------------------------------------------------------------
// 16-wave split-bf16 GEMM — 2-TILE BLOCKS (1 barrier per 2 tiles, 64 MFMA).
// 256x256 tile, BK=32, 16 waves (4Mx4N), ring-4 LDS slots. (R16 = best.)
// SWZ=1: XCD grid (layer 1). SWZ=2: XCD-pinned A-panels + split-K (layer 2).
// ---------------------------------------------------------------------------
extern __shared__ char smem8p[];

#define MFMA8(I0, I1, A0, A1)                                                       \
    acc[I0][0] = __builtin_amdgcn_mfma_f32_16x16x32_bf16(A0, b0, acc[I0][0], 0, 0, 0); \
    acc[I0][1] = __builtin_amdgcn_mfma_f32_16x16x32_bf16(A0, b1, acc[I0][1], 0, 0, 0); \
    acc[I0][2] = __builtin_amdgcn_mfma_f32_16x16x32_bf16(A0, b2, acc[I0][2], 0, 0, 0); \
    acc[I0][3] = __builtin_amdgcn_mfma_f32_16x16x32_bf16(A0, b3, acc[I0][3], 0, 0, 0); \
    acc[I1][0] = __builtin_amdgcn_mfma_f32_16x16x32_bf16(A1, b0, acc[I1][0], 0, 0, 0); \
    acc[I1][1] = __builtin_amdgcn_mfma_f32_16x16x32_bf16(A1, b1, acc[I1][1], 0, 0, 0); \
    acc[I1][2] = __builtin_amdgcn_mfma_f32_16x16x32_bf16(A1, b2, acc[I1][2], 0, 0, 0); \
    acc[I1][3] = __builtin_amdgcn_mfma_f32_16x16x32_bf16(A1, b3, acc[I1][3], 0, 0, 0);

template <int EPI, int SWZ>
__global__ __launch_bounds__(1024, 4) void gemm8p(
    const u16* __restrict__ A, const u16* __restrict__ B,
    const float* __restrict__ biasL, const float* __restrict__ biasR,
    u16* __restrict__ OutU, float* __restrict__ P01, float* __restrict__ P23,
    int Kc, int KcLog, int NH, int nt)
{
    char* ldsA = smem8p;
    char* ldsB = smem8p + 65536;

    const int tid = threadIdx.x;
    const int w = tid >> 6, lane = tid & 63;
    const int wr = w >> 2, wc = w & 3;
    const int fr = lane & 15, kb = lane >> 4;

    int bx, by, z;
    if (SWZ == 1) {
        int b = blockIdx.x;
        int xcd = b & 7, idx = b >> 3;
        bx = 4 * xcd + (idx & 3);
        by = idx >> 2;
        z = 0;
    } else if (SWZ == 2) {
        int b = blockIdx.x;
        by = b & 7;
        int s = b >> 3;
        bx = s & 7;
        z = s >> 3;
    } else {
        bx = blockIdx.x; by = blockIdx.y; z = blockIdx.z;
    }
    const int n0 = bx * 256, m0 = by * 256;
    const size_t K4 = 4 * (size_t)Kc;

    const int srow = tid >> 2;
    const int lk8 = (((tid & 3) ^ ((tid >> 3) & 3))) * 8;
    const int wb = w * 1024;
    const int laneOff = fr * 64 + ((kb ^ ((fr >> 1) & 3)) << 4);

    f32x4 acc[4][4];
#pragma unroll
    for (int i = 0; i < 4; i++)
#pragma unroll
        for (int j = 0; j < 4; j++)
            acc[i][j] = (f32x4){0.f, 0.f, 0.f, 0.f};

    const int t0 = z * nt, te = t0 + nt;   // nt even

    auto colA = [&](int t) {
        int k0 = t << 5;
        int seg = k0 >> KcLog, kk = k0 & (Kc - 1);
        int r3 = seg >= 3 ? seg - 3 : seg;
        int bs = seg >= 3 ? 2 : 0;
        return (bs + (r3 == 1 ? 1 : 0)) * Kc + kk;
    };
    auto colB = [&](int t) {
        int k0 = t << 5;
        int seg = k0 >> KcLog, kk = k0 & (Kc - 1);
        int r3 = seg >= 3 ? seg - 3 : seg;
        int bs = seg >= 3 ? 2 : 0;
        return (bs + (r3 == 2 ? 1 : 0)) * Kc + kk;
    };
    auto stageA = [&](int t) {
        const u16* src = A + (size_t)(m0 + srow) * K4 + colA(t) + lk8;
        gload_lds16(src, ldsA + (t & 3) * 16384 + wb);
    };
    auto stageB = [&](int t) {
        const u16* src = B + (size_t)(n0 + srow) * K4 + colB(t) + lk8;
        gload_lds16(src, ldsB + (t & 3) * 16384 + wb);
    };
    auto aBase = [&](int t) -> const char* {
        return ldsA + (t & 3) * 16384 + wr * 4096 + laneOff;
    };
    auto bBase = [&](int t) -> const char* {
        return ldsB + (t & 3) * 16384 + wc * 4096 + laneOff;
    };

    // prologue: stage tiles t0, t0+1; drain; publish; read tile-t0 frags
    stageA(t0); stageB(t0);
    stageA(t0 + 1); stageB(t0 + 1);
    asm volatile("s_waitcnt vmcnt(0)" ::: "memory");
    asm volatile("s_barrier" ::: "memory");

    bf16x8 a0, a1, b0, b1, b2, b3;
    {
        const char* aS = aBase(t0);
        const char* bS = bBase(t0);
        a0 = *(const bf16x8*)(aS + 0 * 1024);
        a1 = *(const bf16x8*)(aS + 1 * 1024);
        b0 = *(const bf16x8*)(bS + 0 * 1024);
        b1 = *(const bf16x8*)(bS + 1 * 1024);
        b2 = *(const bf16x8*)(bS + 2 * 1024);
        b3 = *(const bf16x8*)(bS + 3 * 1024);
    }

    for (int t = t0; t < te; t += 2) {
        const bool more = (t + 2 < te);

        // stage next block's tiles (slots (t+2)&3, (t+3)&3 — free by barrier)
        if (more) { stageA(t + 2); stageB(t + 2); stageA(t + 3); stageB(t + 3); }

        // ---- tile t ----
        const char* aS = aBase(t);
        bf16x8 c0 = *(const bf16x8*)(aS + 2 * 1024);
        bf16x8 c1 = *(const bf16x8*)(aS + 3 * 1024);
        MFMA8(0, 1, a0, a1)                      // ph1(t): a,b

        {   // a(t+1) — slot confirmed at previous barrier
            const char* aN = aBase(t + 1);
            a0 = *(const bf16x8*)(aN + 0 * 1024);
            a1 = *(const bf16x8*)(aN + 1 * 1024);
        }
        MFMA8(2, 3, c0, c1)                      // ph2(t): c,b

        // ---- tile t+1 ----
        {   // b(t+1) (b regs free after ph2(t)), c(t+1)
            const char* bN = bBase(t + 1);
            b0 = *(const bf16x8*)(bN + 0 * 1024);
            b1 = *(const bf16x8*)(bN + 1 * 1024);
            b2 = *(const bf16x8*)(bN + 2 * 1024);
            b3 = *(const bf16x8*)(bN + 3 * 1024);
            const char* aN = aBase(t + 1);
            c0 = *(const bf16x8*)(aN + 2 * 1024);
            c1 = *(const bf16x8*)(aN + 3 * 1024);
        }
        MFMA8(0, 1, a0, a1)                      // ph1(t+1)
        MFMA8(2, 3, c0, c1)                      // ph2(t+1)

        if (more) {
            // drain own stages of t+2,t+3, then publish to all waves
            asm volatile("s_waitcnt vmcnt(0)" ::: "memory");
            asm volatile("s_barrier" ::: "memory");
            // block-entry reads for tile t+2 (only exposed reads per block)
            const char* aN = aBase(t + 2);
            const char* bN = bBase(t + 2);
            a0 = *(const bf16x8*)(aN + 0 * 1024);
            a1 = *(const bf16x8*)(aN + 1 * 1024);
            b0 = *(const bf16x8*)(bN + 0 * 1024);
            b1 = *(const bf16x8*)(bN + 1 * 1024);
            b2 = *(const bf16x8*)(bN + 2 * 1024);
            b3 = *(const bf16x8*)(bN + 3 * 1024);
        }
    }

    // ---- epilogue (wave-tile 64x64 at (wr*64, wc*64)) ----
    const int fq = kb;
#pragma unroll
    for (int nj = 0; nj < 4; nj++) {
        int n = n0 + wc * 64 + nj * 16 + fr;
        if (EPI == 0) {
            bool left = (n < NH);
            int nn = left ? n : (n - NH);
            float bias = left ? biasL[n] : biasR[nn];
#pragma unroll
            for (int mi = 0; mi < 4; mi++) {
                int mb = m0 + wr * 64 + mi * 16 + fq * 4;
#pragma unroll
                for (int r = 0; r < 4; r++) {
                    float val = fmaxf(acc[mi][nj][r] + bias, 0.f);
                    u16 h = f2bf(val);
                    u16 lo = f2bf(val - bf2f(h));
                    size_t rb = (size_t)(mb + r) * (4 * (size_t)NH);
                    if (left) { OutU[rb + nn] = h; OutU[rb + NH + nn] = lo; }
                    else { OutU[rb + 2 * (size_t)NH + nn] = h; OutU[rb + 3 * (size_t)NH + nn] = lo; }
                }
            }
        } else {
            const size_t PSZ = (size_t)2048 * 2048;
            float* Out = (z < 2) ? (P01 + (size_t)z * PSZ) : (P23 + (size_t)(z - 2) * PSZ);
#pragma unroll
            for (int mi = 0; mi < 4; mi++) {
                int mb = m0 + wr * 64 + mi * 16 + fq * 4;
#pragma unroll
                for (int r = 0; r < 4; r++)
                    Out[(size_t)(mb + r) * 2048 + n] = acc[mi][nj][r];
            }
        }
    }
}

// ---------------------------------------------------------------------------
// Router, 8 rows/block
// ---------------------------------------------------------------------------
__global__ __launch_bounds__(256) void router_kernel(
    const float* __restrict__ P01, const float* __restrict__ P23, int ZK,
    const float* __restrict__ b2,
    const float* __restrict__ w_gate, const float* __restrict__ w_noise,
    const float* __restrict__ noise_z, float* __restrict__ gates)
{
    __shared__ float s_amp[8][1024];
    __shared__ float s_dot[8][176];
    __shared__ float s_lg[8][88];
    __shared__ int   s_idx[8][3];
    __shared__ float s_val[8][3];

    const int tid = threadIdx.x;
    const int r0 = blockIdx.x * 8;
    const size_t PSZ = (size_t)2048 * 2048;

    for (int idx = tid; idx < 8 * 1024; idx += 256) {
        int row = idx >> 10, i = idx & 1023;
        size_t roff = (size_t)(r0 + row) * 2048;
        float orr = b2[i];
        float oii = b2[1024 + i];
        for (int zz = 0; zz < ZK; zz++) {
            const float* Pz = ((zz < 2) ? (P01 + (size_t)zz * PSZ)
                                        : (P23 + (size_t)(zz - 2) * PSZ)) + roff;
            orr += Pz[i];
            oii += Pz[1024 + i];
        }
        s_amp[row][i] = sqrtf(orr * orr + oii * oii);
    }
    __syncthreads();

    for (int idx = tid; idx < 8 * 176; idx += 256) {
        int row = idx / 176, c = idx % 176;
        const float* wcol = (c < 88) ? (w_gate + c) : (w_noise + (c - 88));
        float s = 0.f;
        const float4* av = (const float4*)s_amp[row];
        for (int k4 = 0; k4 < 256; k4++) {
            float4 a = av[k4];
            int k = k4 * 4;
            s = fmaf(a.x, wcol[(size_t)(k + 0) * 88], s);
            s = fmaf(a.y, wcol[(size_t)(k + 1) * 88], s);
            s = fmaf(a.z, wcol[(size_t)(k + 2) * 88], s);
            s = fmaf(a.w, wcol[(size_t)(k + 3) * 88], s);
        }
        s_dot[row][c] = s;
    }
    __syncthreads();

    for (int idx = tid; idx < 8 * 88; idx += 256) {
        int row = idx / 88, c = idx % 88;
        float cn = s_dot[row][88 + c];
        float ns = (cn > 20.f) ? cn : log1pf(expf(cn));
        ns += 0.01f;
        s_lg[row][c] = s_dot[row][c] + noise_z[(size_t)(r0 + row) * 88 + c] * ns;
    }
    __syncthreads();

    if (tid < 8) {
        int i0 = -1, i1 = -1, i2 = -1;
        float v0 = -1e30f, v1 = -1e30f, v2 = -1e30f;
        for (int i = 0; i < P_DIM; i++) {
            float t = s_lg[tid][i];
            if (t > v0) { v0 = t; i0 = i; }
        }
        for (int i = 0; i < P_DIM; i++) {
            if (i == i0) continue;
            float t = s_lg[tid][i];
            if (t > v1) { v1 = t; i1 = i; }
        }
        for (int i = 0; i < P_DIM; i++) {
            if (i == i0 || i == i1) continue;
            float t = s_lg[tid][i];
            if (t > v2) { v2 = t; i2 = i; }
        }
        s_idx[tid][0] = i0; s_idx[tid][1] = i1; s_idx[tid][2] = i2;
        s_val[tid][0] = v0; s_val[tid][1] = v1; s_val[tid][2] = v2;
    }
    __syncthreads();

    for (int idx = tid; idx < 8 * 88; idx += 256) {
        int row = idx / 88, c = idx % 88;
        float m = s_val[row][0];
        float e0 = expf(s_val[row][0] - m);
        float e1 = expf(s_val[row][1] - m);
        float e2 = expf(s_val[row][2] - m);
        float inv = 1.f / (e0 + e1 + e2);
        float g = 0.f;
        if (c == s_idx[row][0]) g = e0 * inv;
        else if (c == s_idx[row][1]) g = e1 * inv;
        else if (c == s_idx[row][2]) g = e2 * inv;
        gates[(size_t)(r0 + row) * 88 + c] = g;
    }
}

// ---------------------------------------------------------------------------
extern "C" void kernel_launch(void* const* d_in, const int* in_sizes, int n_in,
                              void* d_out, int out_size, void* d_ws, size_t ws_size,
                              hipStream_t stream)
{
    const float* x       = (const float*)d_in[0];
    const float* w_start = (const float*)d_in[1];
    const float* b_start = (const float*)d_in[2];
    const float* w1      = (const float*)d_in[3];
    const float* b1      = (const float*)d_in[4];
    const float* w2      = (const float*)d_in[5];
    const float* b2      = (const float*)d_in[6];
    const float* w_gate  = (const float*)d_in[7];
    const float* w_noise = (const float*)d_in[8];
    const float* noise_z = (const float*)d_in[9];
    float* gates = (float*)d_out;

    const size_t MB = 1024 * 1024;
    char* base = (char*)d_ws;

    hipFuncSetAttribute(reinterpret_cast<const void*>(&gemm8p<0, 1>),
                        hipFuncAttributeMaxDynamicSharedMemorySize, 131072);
    hipFuncSetAttribute(reinterpret_cast<const void*>(&gemm8p<1, 2>),
                        hipFuncAttributeMaxDynamicSharedMemorySize, 131072);

    if (ws_size >= (size_t)208 * MB) {
        // fused layout: BT1[0,64) A1[64,80) BT2[80,144) A2[144,208);
        // P01 [0,32), P23 [32,64) overlay BT1 after gemm1.
        u16*  BT1 = (u16*)base;
        u16*  A1  = (u16*)(base + 64 * MB);
        u16*  BT2 = (u16*)(base + 80 * MB);
        u16*  A2  = (u16*)(base + 144 * MB);
        float* P01 = (float*)base;
        float* P23 = (float*)(base + 32 * MB);

        prep_kernel<<<1024 + 4096 + 4096, 256, 0, stream>>>(
            x, w_start, b_start, A1, w1, BT1, w2, BT2);

        gemm8p<0, 1><<<256, 1024, 131072, stream>>>(
            A1, BT1, b1, b1 + H_DIM, A2, nullptr, nullptr, F_DIM, 10, H_DIM, 192);

        gemm8p<1, 2><<<64 * 4, 1024, 131072, stream>>>(
            A2, BT2, nullptr, nullptr, nullptr, P01, P23, H_DIM, 12, F_DIM, 192);

        router_kernel<<<B_DIM / 8, 256, 0, stream>>>(
            P01, P23, 4, b2, w_gate, w_noise, noise_z, gates);
    } else {
        // fallback layout: A1[16,32) BT[32,96) A2[96,160); P01[0,32) P23[160,192)
        u16*  A1  = (u16*)(base + 16 * MB);
        u16*  BT  = (u16*)(base + 32 * MB);
        u16*  A2  = (u16*)(base + 96 * MB);
        float* P01 = (float*)base;
        float* P23 = (float*)(base + 160 * MB);
        int ZK = (ws_size >= (size_t)192 * MB) ? 4 : 2;

        prep_kernel<<<1024 + 4096, 256, 0, stream>>>(
            x, w_start, b_start, A1, w1, BT, w2, BT /*unused range*/);

        gemm8p<0, 1><<<256, 1024, 131072, stream>>>(
            A1, BT, b1, b1 + H_DIM, A2, nullptr, nullptr, F_DIM, 10, H_DIM, 192);

        conv_bt_kernel<<<dim3(H_DIM / 32, F_DIM / 32), dim3(32, 8), 0, stream>>>(
            w2, BT, H_DIM, F_DIM);
        gemm8p<1, 2><<<64 * ZK, 1024, 131072, stream>>>(
            A2, BT, nullptr, nullptr, nullptr, P01, P23, H_DIM, 12, F_DIM, 768 / ZK);

        router_kernel<<<B_DIM / 8, 256, 0, stream>>>(
            P01, P23, ZK, b2, w_gate, w_noise, noise_z, gates);
    }
}